// Round 1
// baseline (761.624 us; speedup 1.0000x reference)
//
#include <hip/hip_runtime.h>
#include <hip/hip_bf16.h>

typedef __bf16 bf16;
typedef bf16 bf16x8 __attribute__((ext_vector_type(8)));
typedef float f32x4 __attribute__((ext_vector_type(4)));

constexpr int SEQ  = 2048;
constexpr int BAT  = 4;
constexpr int DIM  = 512;
constexpr int NH   = 8;
constexpr int NTOK = SEQ * BAT;   // 8192

// ---------------------------------------------------------------------------
// async global->LDS 16B copy (wave-uniform LDS base + lane*16)
// ---------------------------------------------------------------------------
__device__ inline void async_lds16(const void* g, void* l) {
  __builtin_amdgcn_global_load_lds(
      (__attribute__((address_space(1))) void*)(g),
      (__attribute__((address_space(3))) void*)(l), 16, 0, 0);
}

// ---------------------------------------------------------------------------
// Generic bf16 MFMA GEMM:  C[m,n] = act( (sum_k A[m,k]*Bt[n,k] + bias[n]) * scale )
// A: [M,K] row-major bf16 (stride lda), Bt: [N,K] row-major bf16 (stride ldb)
// 128x128 tile, BK=32, 4 waves, 16x16x32 MFMA.  flags: bit0 = bf16 out, bit1 = relu
// grid = (N/128, M/128, Z); per-z element offsets sAz/sBz/sCz.
// ---------------------------------------------------------------------------
__global__ __launch_bounds__(256)
void gemm_bt(const bf16* __restrict__ A, const bf16* __restrict__ B,
             void* __restrict__ C, const float* __restrict__ bias,
             int K, int lda, int ldb, int ldc,
             long sAz, long sBz, long sCz,
             float scale, int flags) {
  __shared__ __align__(16) bf16 As[128 * 32];
  __shared__ __align__(16) bf16 Bs[128 * 32];

  const int tid  = threadIdx.x;
  const int lane = tid & 63;
  const int w    = tid >> 6;
  const int wr   = w >> 1, wc = w & 1;
  const long z   = blockIdx.z;

  const bf16* Ab = A + (long)blockIdx.y * 128 * lda + z * sAz;
  const bf16* Bb = B + (long)blockIdx.x * 128 * ldb + z * sBz;

  f32x4 acc[4][4] = {};

  // staging chunks: chunk c covers LDS bytes [c*16, c*16+16) of an 8KB tile
  const int c0 = (w * 2 + 0) * 64 + lane;
  const int c1 = (w * 2 + 1) * 64 + lane;
  const int r0 = c0 >> 2, o0 = (c0 & 3) * 8;
  const int r1 = c1 >> 2, o1 = (c1 & 3) * 8;
  bf16* lA0 = As + (w * 2 + 0) * 512;
  bf16* lA1 = As + (w * 2 + 1) * 512;
  bf16* lB0 = Bs + (w * 2 + 0) * 512;
  bf16* lB1 = Bs + (w * 2 + 1) * 512;

  const int r16 = lane & 15, kq = lane >> 4;

  for (int k0 = 0; k0 < K; k0 += 32) {
    async_lds16(Ab + (long)r0 * lda + k0 + o0, lA0);
    async_lds16(Ab + (long)r1 * lda + k0 + o1, lA1);
    async_lds16(Bb + (long)r0 * ldb + k0 + o0, lB0);
    async_lds16(Bb + (long)r1 * ldb + k0 + o1, lB1);
    __syncthreads();

    bf16x8 areg[4], breg[4];
#pragma unroll
    for (int i = 0; i < 4; i++)
      areg[i] = *(const bf16x8*)&As[(wr * 64 + i * 16 + r16) * 32 + kq * 8];
#pragma unroll
    for (int j = 0; j < 4; j++)
      breg[j] = *(const bf16x8*)&Bs[(wc * 64 + j * 16 + r16) * 32 + kq * 8];
#pragma unroll
    for (int i = 0; i < 4; i++)
#pragma unroll
      for (int j = 0; j < 4; j++)
        acc[i][j] = __builtin_amdgcn_mfma_f32_16x16x32_bf16(areg[i], breg[j], acc[i][j], 0, 0, 0);
    __syncthreads();
  }

  // epilogue: C frag layout col = lane&15, row = (lane>>4)*4 + reg   [m89-verified]
  const long rowBase = (long)blockIdx.y * 128 + wr * 64;
  const int  colBase = blockIdx.x * 128 + wc * 64;
  float* Cf = (float*)C;
  bf16*  Cb = (bf16*)C;
  const int rq = lane >> 4;
#pragma unroll
  for (int i = 0; i < 4; i++) {
#pragma unroll
    for (int j = 0; j < 4; j++) {
      const int col = colBase + j * 16 + r16;
      const float bv = bias ? bias[col] : 0.f;
#pragma unroll
      for (int rg = 0; rg < 4; rg++) {
        const long row = rowBase + i * 16 + rq * 4 + rg;
        float y = (acc[i][j][rg] + bv) * scale;
        if (flags & 2) y = fmaxf(y, 0.f);
        const long idx = z * sCz + row * (long)ldc + col;
        if (flags & 1) Cb[idx] = (bf16)y;
        else           Cf[idx] = y;
      }
    }
  }
}

// ---------------------------------------------------------------------------
// f32 [K][N] -> bf16 [N][K] transpose (all dims multiples of 32)
// ---------------------------------------------------------------------------
__global__ void transpose_w_kernel(const float* __restrict__ in, bf16* __restrict__ out,
                                   int K, int N) {
  __shared__ float t[32][33];
  const int n0 = blockIdx.x * 32, k0 = blockIdx.y * 32;
  const int tx = threadIdx.x, ty = threadIdx.y;
#pragma unroll
  for (int i = ty; i < 32; i += 8)
    t[i][tx] = in[(long)(k0 + i) * N + n0 + tx];
  __syncthreads();
#pragma unroll
  for (int i = ty; i < 32; i += 8)
    out[(long)(n0 + i) * K + k0 + tx] = (bf16)t[tx][i];
}

// v bf16 [B*S][512] (token-major) -> vT bf16 [B][512][S]
__global__ void transpose_v_kernel(const bf16* __restrict__ v, bf16* __restrict__ vT) {
  __shared__ bf16 t[32][33];
  const int s0 = blockIdx.x * 32, c0 = blockIdx.y * 32, b = blockIdx.z;
  const int tx = threadIdx.x, ty = threadIdx.y;
#pragma unroll
  for (int i = ty; i < 32; i += 8)
    t[i][tx] = v[((long)b * SEQ + s0 + i) * 512 + c0 + tx];
  __syncthreads();
#pragma unroll
  for (int i = ty; i < 32; i += 8)
    vT[(long)b * 512 * SEQ + (long)(c0 + i) * SEQ + s0 + tx] = t[tx][i];
}

// x f32 [S][B][D] -> xb bf16 [B*S][D]  (token = b*S+s)
__global__ __launch_bounds__(256)
void convert_x_kernel(const float* __restrict__ x, bf16* __restrict__ xb) {
  const long i0 = ((long)blockIdx.x * 256 + threadIdx.x) * 8;
  const int t = (int)(i0 >> 9), d = (int)(i0 & 511);
  const int b = t >> 11, s = t & 2047;
  const float* src = x + ((long)(s * BAT + b) << 9) + d;
  const float4 f0 = *(const float4*)(src);
  const float4 f1 = *(const float4*)(src + 4);
  bf16x8 o;
  o[0] = (bf16)f0.x; o[1] = (bf16)f0.y; o[2] = (bf16)f0.z; o[3] = (bf16)f0.w;
  o[4] = (bf16)f1.x; o[5] = (bf16)f1.y; o[6] = (bf16)f1.z; o[7] = (bf16)f1.w;
  *(bf16x8*)&xb[i0] = o;
}

// in-place row softmax over 2048 bf16 elements; one block per row
__global__ __launch_bounds__(256)
void softmax_kernel(bf16* __restrict__ p) {
  __shared__ float red[8];
  bf16* pr = p + (long)blockIdx.x * 2048;
  const int tid = threadIdx.x, lane = tid & 63, wid = tid >> 6;
  bf16x8 v = *(bf16x8*)&pr[tid * 8];
  float f[8];
#pragma unroll
  for (int j = 0; j < 8; j++) f[j] = (float)v[j];
  float m = f[0];
#pragma unroll
  for (int j = 1; j < 8; j++) m = fmaxf(m, f[j]);
  for (int o = 1; o < 64; o <<= 1) m = fmaxf(m, __shfl_xor(m, o));
  if (lane == 0) red[wid] = m;
  __syncthreads();
  m = fmaxf(fmaxf(red[0], red[1]), fmaxf(red[2], red[3]));
  float sum = 0.f;
#pragma unroll
  for (int j = 0; j < 8; j++) { f[j] = __expf(f[j] - m); sum += f[j]; }
  for (int o = 1; o < 64; o <<= 1) sum += __shfl_xor(sum, o);
  if (lane == 0) red[4 + wid] = sum;
  __syncthreads();
  sum = red[4] + red[5] + red[6] + red[7];
  const float inv = 1.f / sum;
#pragma unroll
  for (int j = 0; j < 8; j++) v[j] = (bf16)(f[j] * inv);
  *(bf16x8*)&pr[tid * 8] = v;
}

// ---------------------------------------------------------------------------
// Stage-2 composition: one wave per (h,s).
// logit_r = sum_d out[r,d] * wq[d] + (bkv.qv)  with wq = Wkv @ qv
// o[d] = sum_r softmax_r(logit) * out[r,d]
// ---------------------------------------------------------------------------
__global__ __launch_bounds__(256)
void stage2_kernel(const bf16* __restrict__ outbuf,   // [NH][SEQ][512] (this batch)
                   const bf16* __restrict__ qvb,      // [NTOK][256]
                   const float* __restrict__ Wkv,     // [64][32]
                   const float* __restrict__ bkv,     // [32]
                   bf16* __restrict__ attn,           // [NTOK][512]
                   int tokenBase) {
  const int lane = threadIdx.x & 63, wid = threadIdx.x >> 6;
  const int g = blockIdx.x * 4 + wid;
  const int h = g >> 11, s = g & 2047;
  const int token = tokenBase + s;

  const bf16* qv = qvb + (long)token * 256 + h * 32;
  const float* wrow = Wkv + lane * 32;
  float wq = 0.f, cb = 0.f;
#pragma unroll 8
  for (int q = 0; q < 32; q++) {
    const float qf = (float)qv[q];
    wq += wrow[q] * qf;
    cb += bkv[q] * qf;
  }

  const bf16* orow = outbuf + ((long)(h << 11) + s) * 512;
  float of[8], lg[8];
#pragma unroll
  for (int r = 0; r < 8; r++) {
    of[r] = (float)orow[r * 64 + lane];
    float p = of[r] * wq;
    for (int o = 1; o < 64; o <<= 1) p += __shfl_xor(p, o);
    lg[r] = p + cb;
  }
  float m = lg[0];
#pragma unroll
  for (int r = 1; r < 8; r++) m = fmaxf(m, lg[r]);
  float e[8], sum = 0.f;
#pragma unroll
  for (int r = 0; r < 8; r++) { e[r] = __expf(lg[r] - m); sum += e[r]; }
  const float inv = 1.f / sum;
  float o = 0.f;
#pragma unroll
  for (int r = 0; r < 8; r++) o += e[r] * inv * of[r];
  attn[(long)token * 512 + h * 64 + lane] = (bf16)o;
}

// ---------------------------------------------------------------------------
// LayerNorm over D=512 per token. a: token-major GEMM out; bres: residual.
// bresT: residual indexed in [S][B][D] layout; outT: write d_out in [S][B][D].
// ---------------------------------------------------------------------------
__global__ __launch_bounds__(256)
void ln_kernel(const float* __restrict__ a, const float* __restrict__ bres, int bresT,
               const float* __restrict__ g, const float* __restrict__ be,
               float* __restrict__ outF, bf16* __restrict__ outB, int outT) {
  __shared__ float red[8];
  const int t = blockIdx.x, tid = threadIdx.x;
  const int b = t >> 11, s = t & 2047;
  const long ti = (long)t * 512;
  const long xi = (long)(s * BAT + b) * 512;
  const long ri = bresT ? xi : ti;
  const float v0 = a[ti + tid]       + bres[ri + tid];
  const float v1 = a[ti + 256 + tid] + bres[ri + 256 + tid];
  float sum = v0 + v1, sq = v0 * v0 + v1 * v1;
  const int lane = tid & 63, wid = tid >> 6;
  for (int o = 1; o < 64; o <<= 1) { sum += __shfl_xor(sum, o); sq += __shfl_xor(sq, o); }
  if (lane == 0) { red[wid] = sum; red[4 + wid] = sq; }
  __syncthreads();
  sum = red[0] + red[1] + red[2] + red[3];
  sq  = red[4] + red[5] + red[6] + red[7];
  const float mu = sum * (1.f / 512.f);
  const float var = sq * (1.f / 512.f) - mu * mu;
  const float rs = rsqrtf(var + 1e-5f);
  const float y0 = (v0 - mu) * rs * g[tid] + be[tid];
  const float y1 = (v1 - mu) * rs * g[tid + 256] + be[tid + 256];
  const long oi = outT ? xi : ti;
  if (outF) { outF[oi + tid] = y0; outF[oi + 256 + tid] = y1; }
  if (outB) { outB[ti + tid] = (bf16)y0; outB[ti + 256 + tid] = (bf16)y1; }
}

// ---------------------------------------------------------------------------
extern "C" void kernel_launch(void* const* d_in, const int* in_sizes, int n_in,
                              void* d_out, int out_size, void* d_ws, size_t ws_size,
                              hipStream_t stream) {
  const float* x   = (const float*)d_in[0];
  const float* Wq  = (const float*)d_in[1];
  const float* bq  = (const float*)d_in[2];
  const float* Wk  = (const float*)d_in[3];
  const float* bk  = (const float*)d_in[4];
  const float* Wv  = (const float*)d_in[5];
  const float* bv  = (const float*)d_in[6];
  const float* Wqv = (const float*)d_in[7];
  const float* bqv = (const float*)d_in[8];
  const float* Wkv = (const float*)d_in[9];
  const float* bkv = (const float*)d_in[10];
  const float* Wf  = (const float*)d_in[11];
  const float* bfc = (const float*)d_in[12];
  const float* W1  = (const float*)d_in[13];
  const float* b1  = (const float*)d_in[14];
  const float* W2  = (const float*)d_in[15];
  const float* b2  = (const float*)d_in[16];
  const float* g1  = (const float*)d_in[17];
  const float* be1 = (const float*)d_in[18];
  const float* g2  = (const float*)d_in[19];
  const float* be2 = (const float*)d_in[20];

  char* ws = (char*)d_ws;
  size_t off = 0;
  auto alloc = [&](size_t bytes) -> void* {
    void* p = ws + off;
    off += (bytes + 1023) & ~(size_t)1023;
    return p;
  };
  bf16*  xb   = (bf16*)alloc((size_t)NTOK * 512 * 2);
  bf16*  qb   = (bf16*)alloc((size_t)NTOK * 512 * 2);
  bf16*  kb   = (bf16*)alloc((size_t)NTOK * 512 * 2);
  bf16*  vb   = (bf16*)alloc((size_t)NTOK * 512 * 2);
  bf16*  qvb  = (bf16*)alloc((size_t)NTOK * 256 * 2);
  bf16*  vT   = (bf16*)alloc((size_t)BAT * 512 * SEQ * 2);
  bf16*  WqT  = (bf16*)alloc(512 * 512 * 2);
  bf16*  WkT  = (bf16*)alloc(512 * 512 * 2);
  bf16*  WvT  = (bf16*)alloc(512 * 512 * 2);
  bf16*  WqvT = (bf16*)alloc(256 * 512 * 2);
  bf16*  WfT  = (bf16*)alloc(512 * 512 * 2);
  bf16*  W1T  = (bf16*)alloc((size_t)2048 * 512 * 2);
  bf16*  W2T  = (bf16*)alloc((size_t)512 * 2048 * 2);
  bf16*  attn = (bf16*)alloc((size_t)NTOK * 512 * 2);
  float* wfo  = (float*)alloc((size_t)NTOK * 512 * 4);   // aliased by ffn2 out
  float* ln1f = (float*)alloc((size_t)NTOK * 512 * 4);
  bf16*  ln1b = (bf16*)alloc((size_t)NTOK * 512 * 2);
  bf16*  outb = (bf16*)alloc((size_t)NH * SEQ * 512 * 2);
  bf16*  pbuf = (bf16*)alloc((size_t)NH * SEQ * SEQ * 2); // aliased by ffn1 out
  bf16*  ffn1 = pbuf;
  float* ffn2 = wfo;

  const dim3 tb(32, 8);
  transpose_w_kernel<<<dim3(16, 16), tb, 0, stream>>>(Wq,  WqT,  512, 512);
  transpose_w_kernel<<<dim3(16, 16), tb, 0, stream>>>(Wk,  WkT,  512, 512);
  transpose_w_kernel<<<dim3(16, 16), tb, 0, stream>>>(Wv,  WvT,  512, 512);
  transpose_w_kernel<<<dim3(8, 16),  tb, 0, stream>>>(Wqv, WqvT, 512, 256);
  transpose_w_kernel<<<dim3(16, 16), tb, 0, stream>>>(Wf,  WfT,  512, 512);
  transpose_w_kernel<<<dim3(64, 16), tb, 0, stream>>>(W1,  W1T,  512, 2048);
  transpose_w_kernel<<<dim3(16, 64), tb, 0, stream>>>(W2,  W2T,  2048, 512);

  convert_x_kernel<<<2048, 256, 0, stream>>>(x, xb);

  // projections (q pre-scaled by 1/sqrt(64), qv by 1/sqrt(32))
  gemm_bt<<<dim3(4, 64, 1), 256, 0, stream>>>(xb, WqT,  qb,  bq,  512, 512, 512, 512, 0, 0, 0, 0.125f, 1);
  gemm_bt<<<dim3(4, 64, 1), 256, 0, stream>>>(xb, WkT,  kb,  bk,  512, 512, 512, 512, 0, 0, 0, 1.f, 1);
  gemm_bt<<<dim3(4, 64, 1), 256, 0, stream>>>(xb, WvT,  vb,  bv,  512, 512, 512, 512, 0, 0, 0, 1.f, 1);
  gemm_bt<<<dim3(2, 64, 1), 256, 0, stream>>>(xb, WqvT, qvb, bqv, 512, 512, 512, 256, 0, 0, 0, 0.17677669529663687f, 1);

  transpose_v_kernel<<<dim3(64, 16, 4), tb, 0, stream>>>(vb, vT);

  for (int b = 0; b < BAT; b++) {
    const bf16* qbB = qb + (size_t)b * SEQ * 512;
    const bf16* kbB = kb + (size_t)b * SEQ * 512;
    // score: [2048,64] x [2048,64]^T per head -> bf16 logits [h][s][t]
    gemm_bt<<<dim3(16, 16, 8), 256, 0, stream>>>(qbB, kbB, pbuf, nullptr,
        64, 512, 512, 2048, 64, 64, (long)SEQ * SEQ, 1.f, 1);
    softmax_kernel<<<NH * SEQ, 256, 0, stream>>>(pbuf);
    // PV: P[s,t] @ Vall[t, r*64+d]  (vT = Vall^T)
    gemm_bt<<<dim3(4, 16, 8), 256, 0, stream>>>(pbuf, vT + (size_t)b * 512 * SEQ, outb, nullptr,
        2048, 2048, 2048, 512, (long)SEQ * SEQ, 0, (long)SEQ * 512, 1.f, 1);
    stage2_kernel<<<NH * SEQ / 4, 256, 0, stream>>>(outb, qvb, Wkv, bkv, attn, b * SEQ);
  }

  gemm_bt<<<dim3(4, 64, 1), 256, 0, stream>>>(attn, WfT, wfo, bfc, 512, 512, 512, 512, 0, 0, 0, 1.f, 0);
  ln_kernel<<<NTOK, 256, 0, stream>>>(wfo, x, 1, g1, be1, ln1f, ln1b, 0);
  gemm_bt<<<dim3(16, 64, 1), 256, 0, stream>>>(ln1b, W1T, ffn1, b1, 512, 512, 512, 2048, 0, 0, 0, 1.f, 1 | 2);
  gemm_bt<<<dim3(4, 64, 1), 256, 0, stream>>>(ffn1, W2T, ffn2, b2, 2048, 2048, 2048, 512, 0, 0, 0, 1.f, 0);
  ln_kernel<<<NTOK, 256, 0, stream>>>(ffn2, ln1f, 0, g2, be2, (float*)d_out, nullptr, 1);
}

// Round 2
// 754.382 us; speedup vs baseline: 1.0096x; 1.0096x over previous
//
#include <hip/hip_runtime.h>
#include <hip/hip_bf16.h>

typedef __bf16 bf16;
typedef bf16 bf16x8 __attribute__((ext_vector_type(8)));
typedef float f32x4 __attribute__((ext_vector_type(4)));

constexpr int SEQ  = 2048;
constexpr int BAT  = 4;
constexpr int DIM  = 512;
constexpr int NH   = 8;
constexpr int NTOK = SEQ * BAT;   // 8192

// ---------------------------------------------------------------------------
// async global->LDS 16B copy (wave-uniform LDS base + lane*16)
// ---------------------------------------------------------------------------
__device__ inline void async_lds16(const void* g, void* l) {
  __builtin_amdgcn_global_load_lds(
      (__attribute__((address_space(1))) void*)(g),
      (__attribute__((address_space(3))) void*)(l), 16, 0, 0);
}

// ---------------------------------------------------------------------------
// Generic bf16 MFMA GEMM:  C[m,n] = act( (sum_k A[m,k]*Bt[n,k] + bias[n]) * scale )
// A: [M,K] row-major bf16 (stride lda), Bt: [N,K] row-major bf16 (stride ldb)
// Tile 128 x BN, BK=32, 16x16x32 MFMA. BN=128 -> 4 waves, BN=256 -> 8 waves.
// LDS slot-swizzle: 16B chunk at (row r, slot s) holds global k-chunk s^((r>>1)&3);
// fragment ds_read applies the same XOR -> 2-way (free) bank aliasing.
// flags: bit0 = bf16 out, bit1 = relu.  grid = (N/BN, M/128, Z).
// ---------------------------------------------------------------------------
template <int BN>
__global__ __launch_bounds__(BN == 256 ? 512 : 256)
void gemm_bt(const bf16* __restrict__ A, const bf16* __restrict__ B,
             void* __restrict__ C, const float* __restrict__ bias,
             int K, int lda, int ldb, int ldc,
             long sAz, long sBz, long sCz,
             float scale, int flags) {
  constexpr int NW = BN / 32;           // 4 or 8 waves
  constexpr int WC = NW / 2;            // wave cols (2 or 4)
  constexpr int AG = 512 / (NW * 64);   // A staging groups per wave
  constexpr int BG = (BN * 4) / (NW * 64); // B staging groups per wave

  __shared__ __align__(16) bf16 As[128 * 32];
  __shared__ __align__(16) bf16 Bs[BN * 32];

  const int tid  = threadIdx.x;
  const int lane = tid & 63;
  const int w    = tid >> 6;
  const int wr   = w / WC, wc = w % WC;
  const long z   = blockIdx.z;

  const bf16* Ab = A + (long)blockIdx.y * 128 * lda + z * sAz;
  const bf16* Bb = B + (long)blockIdx.x * BN * ldb + z * sBz;

  // per-lane staging sources (swizzled slot within each 64B row-chunk group)
  const bf16* aSrc[AG];
#pragma unroll
  for (int g = 0; g < AG; g++) {
    const int c = (w * AG + g) * 64 + lane;
    const int r = c >> 2, sl = c & 3;
    aSrc[g] = Ab + (long)r * lda + ((sl ^ ((r >> 1) & 3)) << 3);
  }
  const bf16* bSrc[BG];
#pragma unroll
  for (int g = 0; g < BG; g++) {
    const int c = (w * BG + g) * 64 + lane;
    const int r = c >> 2, sl = c & 3;
    bSrc[g] = Bb + (long)r * ldb + ((sl ^ ((r >> 1) & 3)) << 3);
  }

  f32x4 acc[4][4] = {};

  const int r16 = lane & 15, kq = lane >> 4;
  const int so = ((kq ^ ((r16 >> 1) & 3)) << 3);  // swizzled element slot

  for (int k0 = 0; k0 < K; k0 += 32) {
#pragma unroll
    for (int g = 0; g < AG; g++)
      async_lds16(aSrc[g] + k0, As + (w * AG + g) * 512);
#pragma unroll
    for (int g = 0; g < BG; g++)
      async_lds16(bSrc[g] + k0, Bs + (w * BG + g) * 512);
    __syncthreads();

    bf16x8 areg[4], breg[4];
#pragma unroll
    for (int i = 0; i < 4; i++)
      areg[i] = *(const bf16x8*)&As[(wr * 64 + i * 16 + r16) * 32 + so];
#pragma unroll
    for (int j = 0; j < 4; j++)
      breg[j] = *(const bf16x8*)&Bs[(wc * 64 + j * 16 + r16) * 32 + so];
#pragma unroll
    for (int i = 0; i < 4; i++)
#pragma unroll
      for (int j = 0; j < 4; j++)
        acc[i][j] = __builtin_amdgcn_mfma_f32_16x16x32_bf16(areg[i], breg[j], acc[i][j], 0, 0, 0);
    __syncthreads();
  }

  // epilogue: C frag layout col = lane&15, row = (lane>>4)*4 + reg   [m89-verified]
  const long rowBase = (long)blockIdx.y * 128 + wr * 64;
  const int  colBase = blockIdx.x * BN + wc * 64;
  float* Cf = (float*)C;
  bf16*  Cb = (bf16*)C;
  const int rq = lane >> 4;
#pragma unroll
  for (int i = 0; i < 4; i++) {
#pragma unroll
    for (int j = 0; j < 4; j++) {
      const int col = colBase + j * 16 + r16;
      const float bv = bias ? bias[col] : 0.f;
#pragma unroll
      for (int rg = 0; rg < 4; rg++) {
        const long row = rowBase + i * 16 + rq * 4 + rg;
        float y = (acc[i][j][rg] + bv) * scale;
        if (flags & 2) y = fmaxf(y, 0.f);
        const long idx = z * sCz + row * (long)ldc + col;
        if (flags & 1) Cb[idx] = (bf16)y;
        else           Cf[idx] = y;
      }
    }
  }
}

// ---------------------------------------------------------------------------
// f32 [K][N] -> bf16 [N][K] transpose (all dims multiples of 32)
// ---------------------------------------------------------------------------
__global__ void transpose_w_kernel(const float* __restrict__ in, bf16* __restrict__ out,
                                   int K, int N) {
  __shared__ float t[32][33];
  const int n0 = blockIdx.x * 32, k0 = blockIdx.y * 32;
  const int tx = threadIdx.x, ty = threadIdx.y;
#pragma unroll
  for (int i = ty; i < 32; i += 8)
    t[i][tx] = in[(long)(k0 + i) * N + n0 + tx];
  __syncthreads();
#pragma unroll
  for (int i = ty; i < 32; i += 8)
    out[(long)(n0 + i) * K + k0 + tx] = (bf16)t[tx][i];
}

// v bf16 [B*S][512] (token-major) -> vT bf16 [B][512][S]
__global__ void transpose_v_kernel(const bf16* __restrict__ v, bf16* __restrict__ vT) {
  __shared__ bf16 t[32][33];
  const int s0 = blockIdx.x * 32, c0 = blockIdx.y * 32, b = blockIdx.z;
  const int tx = threadIdx.x, ty = threadIdx.y;
#pragma unroll
  for (int i = ty; i < 32; i += 8)
    t[i][tx] = v[((long)b * SEQ + s0 + i) * 512 + c0 + tx];
  __syncthreads();
#pragma unroll
  for (int i = ty; i < 32; i += 8)
    vT[(long)b * 512 * SEQ + (long)(c0 + i) * SEQ + s0 + tx] = t[tx][i];
}

// x f32 [S][B][D] -> xb bf16 [B*S][D]  (token = b*S+s)
__global__ __launch_bounds__(256)
void convert_x_kernel(const float* __restrict__ x, bf16* __restrict__ xb) {
  const long i0 = ((long)blockIdx.x * 256 + threadIdx.x) * 8;
  const int t = (int)(i0 >> 9), d = (int)(i0 & 511);
  const int b = t >> 11, s = t & 2047;
  const float* src = x + ((long)(s * BAT + b) << 9) + d;
  const float4 f0 = *(const float4*)(src);
  const float4 f1 = *(const float4*)(src + 4);
  bf16x8 o;
  o[0] = (bf16)f0.x; o[1] = (bf16)f0.y; o[2] = (bf16)f0.z; o[3] = (bf16)f0.w;
  o[4] = (bf16)f1.x; o[5] = (bf16)f1.y; o[6] = (bf16)f1.z; o[7] = (bf16)f1.w;
  *(bf16x8*)&xb[i0] = o;
}

// in-place row softmax over 2048 bf16 elements; one block per row
__global__ __launch_bounds__(256)
void softmax_kernel(bf16* __restrict__ p) {
  __shared__ float red[8];
  bf16* pr = p + (long)blockIdx.x * 2048;
  const int tid = threadIdx.x, lane = tid & 63, wid = tid >> 6;
  bf16x8 v = *(bf16x8*)&pr[tid * 8];
  float f[8];
#pragma unroll
  for (int j = 0; j < 8; j++) f[j] = (float)v[j];
  float m = f[0];
#pragma unroll
  for (int j = 1; j < 8; j++) m = fmaxf(m, f[j]);
  for (int o = 1; o < 64; o <<= 1) m = fmaxf(m, __shfl_xor(m, o));
  if (lane == 0) red[wid] = m;
  __syncthreads();
  m = fmaxf(fmaxf(red[0], red[1]), fmaxf(red[2], red[3]));
  float sum = 0.f;
#pragma unroll
  for (int j = 0; j < 8; j++) { f[j] = __expf(f[j] - m); sum += f[j]; }
  for (int o = 1; o < 64; o <<= 1) sum += __shfl_xor(sum, o);
  if (lane == 0) red[4 + wid] = sum;
  __syncthreads();
  sum = red[4] + red[5] + red[6] + red[7];
  const float inv = 1.f / sum;
#pragma unroll
  for (int j = 0; j < 8; j++) v[j] = (bf16)(f[j] * inv);
  *(bf16x8*)&pr[tid * 8] = v;
}

// ---------------------------------------------------------------------------
// Stage-2 composition: one wave per (h,s).
// logit_r = sum_d out[r,d] * wq[d] + (bkv.qv)  with wq = Wkv @ qv
// o[d] = sum_r softmax_r(logit) * out[r,d]
// ---------------------------------------------------------------------------
__global__ __launch_bounds__(256)
void stage2_kernel(const bf16* __restrict__ outbuf,   // [NH][SEQ][512] (this batch)
                   const bf16* __restrict__ qvb,      // [NTOK][256]
                   const float* __restrict__ Wkv,     // [64][32]
                   const float* __restrict__ bkv,     // [32]
                   bf16* __restrict__ attn,           // [NTOK][512]
                   int tokenBase) {
  const int lane = threadIdx.x & 63, wid = threadIdx.x >> 6;
  const int g = blockIdx.x * 4 + wid;
  const int h = g >> 11, s = g & 2047;
  const int token = tokenBase + s;

  const bf16* qv = qvb + (long)token * 256 + h * 32;
  const float* wrow = Wkv + lane * 32;
  float wq = 0.f, cb = 0.f;
#pragma unroll 8
  for (int q = 0; q < 32; q++) {
    const float qf = (float)qv[q];
    wq += wrow[q] * qf;
    cb += bkv[q] * qf;
  }

  const bf16* orow = outbuf + ((long)(h << 11) + s) * 512;
  float of[8], lg[8];
#pragma unroll
  for (int r = 0; r < 8; r++) {
    of[r] = (float)orow[r * 64 + lane];
    float p = of[r] * wq;
    for (int o = 1; o < 64; o <<= 1) p += __shfl_xor(p, o);
    lg[r] = p + cb;
  }
  float m = lg[0];
#pragma unroll
  for (int r = 1; r < 8; r++) m = fmaxf(m, lg[r]);
  float e[8], sum = 0.f;
#pragma unroll
  for (int r = 0; r < 8; r++) { e[r] = __expf(lg[r] - m); sum += e[r]; }
  const float inv = 1.f / sum;
  float o = 0.f;
#pragma unroll
  for (int r = 0; r < 8; r++) o += e[r] * inv * of[r];
  attn[(long)token * 512 + h * 64 + lane] = (bf16)o;
}

// ---------------------------------------------------------------------------
// LayerNorm over D=512 per token. a: token-major GEMM out; bres: residual.
// bresT: residual indexed in [S][B][D] layout; outT: write d_out in [S][B][D].
// ---------------------------------------------------------------------------
__global__ __launch_bounds__(256)
void ln_kernel(const float* __restrict__ a, const float* __restrict__ bres, int bresT,
               const float* __restrict__ g, const float* __restrict__ be,
               float* __restrict__ outF, bf16* __restrict__ outB, int outT) {
  __shared__ float red[8];
  const int t = blockIdx.x, tid = threadIdx.x;
  const int b = t >> 11, s = t & 2047;
  const long ti = (long)t * 512;
  const long xi = (long)(s * BAT + b) * 512;
  const long ri = bresT ? xi : ti;
  const float v0 = a[ti + tid]       + bres[ri + tid];
  const float v1 = a[ti + 256 + tid] + bres[ri + 256 + tid];
  float sum = v0 + v1, sq = v0 * v0 + v1 * v1;
  const int lane = tid & 63, wid = tid >> 6;
  for (int o = 1; o < 64; o <<= 1) { sum += __shfl_xor(sum, o); sq += __shfl_xor(sq, o); }
  if (lane == 0) { red[wid] = sum; red[4 + wid] = sq; }
  __syncthreads();
  sum = red[0] + red[1] + red[2] + red[3];
  sq  = red[4] + red[5] + red[6] + red[7];
  const float mu = sum * (1.f / 512.f);
  const float var = sq * (1.f / 512.f) - mu * mu;
  const float rs = rsqrtf(var + 1e-5f);
  const float y0 = (v0 - mu) * rs * g[tid] + be[tid];
  const float y1 = (v1 - mu) * rs * g[tid + 256] + be[tid + 256];
  const long oi = outT ? xi : ti;
  if (outF) { outF[oi + tid] = y0; outF[oi + 256 + tid] = y1; }
  if (outB) { outB[ti + tid] = (bf16)y0; outB[ti + 256 + tid] = (bf16)y1; }
}

// ---------------------------------------------------------------------------
extern "C" void kernel_launch(void* const* d_in, const int* in_sizes, int n_in,
                              void* d_out, int out_size, void* d_ws, size_t ws_size,
                              hipStream_t stream) {
  const float* x   = (const float*)d_in[0];
  const float* Wq  = (const float*)d_in[1];
  const float* bq  = (const float*)d_in[2];
  const float* Wk  = (const float*)d_in[3];
  const float* bk  = (const float*)d_in[4];
  const float* Wv  = (const float*)d_in[5];
  const float* bv  = (const float*)d_in[6];
  const float* Wqv = (const float*)d_in[7];
  const float* bqv = (const float*)d_in[8];
  const float* Wkv = (const float*)d_in[9];
  const float* bkv = (const float*)d_in[10];
  const float* Wf  = (const float*)d_in[11];
  const float* bfc = (const float*)d_in[12];
  const float* W1  = (const float*)d_in[13];
  const float* b1  = (const float*)d_in[14];
  const float* W2  = (const float*)d_in[15];
  const float* b2  = (const float*)d_in[16];
  const float* g1  = (const float*)d_in[17];
  const float* be1 = (const float*)d_in[18];
  const float* g2  = (const float*)d_in[19];
  const float* be2 = (const float*)d_in[20];

  char* ws = (char*)d_ws;
  size_t off = 0;
  auto alloc = [&](size_t bytes) -> void* {
    void* p = ws + off;
    off += (bytes + 1023) & ~(size_t)1023;
    return p;
  };
  bf16*  xb   = (bf16*)alloc((size_t)NTOK * 512 * 2);
  bf16*  qb   = (bf16*)alloc((size_t)NTOK * 512 * 2);
  bf16*  kb   = (bf16*)alloc((size_t)NTOK * 512 * 2);
  bf16*  vb   = (bf16*)alloc((size_t)NTOK * 512 * 2);
  bf16*  qvb  = (bf16*)alloc((size_t)NTOK * 256 * 2);
  bf16*  vT   = (bf16*)alloc((size_t)BAT * 512 * SEQ * 2);
  bf16*  WqT  = (bf16*)alloc(512 * 512 * 2);
  bf16*  WkT  = (bf16*)alloc(512 * 512 * 2);
  bf16*  WvT  = (bf16*)alloc(512 * 512 * 2);
  bf16*  WqvT = (bf16*)alloc(256 * 512 * 2);
  bf16*  WfT  = (bf16*)alloc(512 * 512 * 2);
  bf16*  W1T  = (bf16*)alloc((size_t)2048 * 512 * 2);
  bf16*  W2T  = (bf16*)alloc((size_t)512 * 2048 * 2);
  bf16*  attn = (bf16*)alloc((size_t)NTOK * 512 * 2);
  float* wfo  = (float*)alloc((size_t)NTOK * 512 * 4);   // aliased by ffn2 out
  float* ln1f = (float*)alloc((size_t)NTOK * 512 * 4);
  bf16*  ln1b = (bf16*)alloc((size_t)NTOK * 512 * 2);
  bf16*  outb = (bf16*)alloc((size_t)NH * SEQ * 512 * 2);
  bf16*  pbuf = (bf16*)alloc((size_t)NH * SEQ * SEQ * 2); // aliased by ffn1 out
  bf16*  ffn1 = pbuf;
  float* ffn2 = wfo;

  const dim3 tb(32, 8);
  transpose_w_kernel<<<dim3(16, 16), tb, 0, stream>>>(Wq,  WqT,  512, 512);
  transpose_w_kernel<<<dim3(16, 16), tb, 0, stream>>>(Wk,  WkT,  512, 512);
  transpose_w_kernel<<<dim3(16, 16), tb, 0, stream>>>(Wv,  WvT,  512, 512);
  transpose_w_kernel<<<dim3(8, 16),  tb, 0, stream>>>(Wqv, WqvT, 512, 256);
  transpose_w_kernel<<<dim3(16, 16), tb, 0, stream>>>(Wf,  WfT,  512, 512);
  transpose_w_kernel<<<dim3(64, 16), tb, 0, stream>>>(W1,  W1T,  512, 2048);
  transpose_w_kernel<<<dim3(16, 64), tb, 0, stream>>>(W2,  W2T,  2048, 512);

  convert_x_kernel<<<2048, 256, 0, stream>>>(x, xb);

  // projections (q pre-scaled by 1/sqrt(64), qv by 1/sqrt(32))
  gemm_bt<128><<<dim3(4, 64, 1), 256, 0, stream>>>(xb, WqT,  qb,  bq,  512, 512, 512, 512, 0, 0, 0, 0.125f, 1);
  gemm_bt<128><<<dim3(4, 64, 1), 256, 0, stream>>>(xb, WkT,  kb,  bk,  512, 512, 512, 512, 0, 0, 0, 1.f, 1);
  gemm_bt<128><<<dim3(4, 64, 1), 256, 0, stream>>>(xb, WvT,  vb,  bv,  512, 512, 512, 512, 0, 0, 0, 1.f, 1);
  gemm_bt<128><<<dim3(2, 64, 1), 256, 0, stream>>>(xb, WqvT, qvb, bqv, 512, 512, 512, 256, 0, 0, 0, 0.17677669529663687f, 1);

  transpose_v_kernel<<<dim3(64, 16, 4), tb, 0, stream>>>(vb, vT);

  for (int b = 0; b < BAT; b++) {
    const bf16* qbB = qb + (size_t)b * SEQ * 512;
    const bf16* kbB = kb + (size_t)b * SEQ * 512;
    // score: [2048,64] x [2048,64]^T per head -> bf16 logits [h][s][t]
    gemm_bt<256><<<dim3(8, 16, 8), 512, 0, stream>>>(qbB, kbB, pbuf, nullptr,
        64, 512, 512, 2048, 64, 64, (long)SEQ * SEQ, 1.f, 1);
    softmax_kernel<<<NH * SEQ, 256, 0, stream>>>(pbuf);
    // PV: P[s,t] @ Vall[t, r*64+d]  (vT = Vall^T)
    gemm_bt<256><<<dim3(2, 16, 8), 512, 0, stream>>>(pbuf, vT + (size_t)b * 512 * SEQ, outb, nullptr,
        2048, 2048, 2048, 512, (long)SEQ * SEQ, 0, (long)SEQ * 512, 1.f, 1);
    stage2_kernel<<<NH * SEQ / 4, 256, 0, stream>>>(outb, qvb, Wkv, bkv, attn, b * SEQ);
  }

  gemm_bt<128><<<dim3(4, 64, 1), 256, 0, stream>>>(attn, WfT, wfo, bfc, 512, 512, 512, 512, 0, 0, 0, 1.f, 0);
  ln_kernel<<<NTOK, 256, 0, stream>>>(wfo, x, 1, g1, be1, ln1f, ln1b, 0);
  gemm_bt<256><<<dim3(8, 64, 1), 512, 0, stream>>>(ln1b, W1T, ffn1, b1, 512, 512, 512, 2048, 0, 0, 0, 1.f, 1 | 2);
  gemm_bt<128><<<dim3(4, 64, 1), 256, 0, stream>>>(ffn1, W2T, ffn2, b2, 2048, 2048, 2048, 512, 0, 0, 0, 1.f, 0);
  ln_kernel<<<NTOK, 256, 0, stream>>>(ffn2, ln1f, 0, g2, be2, (float*)d_out, nullptr, 1);
}

// Round 3
// 687.772 us; speedup vs baseline: 1.1074x; 1.0968x over previous
//
#include <hip/hip_runtime.h>
#include <hip/hip_bf16.h>

typedef __bf16 bf16;
typedef bf16 bf16x8 __attribute__((ext_vector_type(8)));
typedef float f32x4 __attribute__((ext_vector_type(4)));

constexpr int SEQ  = 2048;
constexpr int BAT  = 4;
constexpr int NH   = 8;
constexpr int NTOK = SEQ * BAT;   // 8192
constexpr int QKVW = 1792;        // fused projection width: 512+512+512+256

// ---------------------------------------------------------------------------
// async global->LDS 16B copy (wave-uniform LDS base + lane*16)
// ---------------------------------------------------------------------------
__device__ inline void async_lds16(const void* g, void* l) {
  __builtin_amdgcn_global_load_lds(
      (__attribute__((address_space(1))) void*)(g),
      (__attribute__((address_space(3))) void*)(l), 16, 0, 0);
}

// ---------------------------------------------------------------------------
// bf16 MFMA GEMM, double-buffered 2-phase pipeline (T3 minimum + T5):
//   C[m,n] = act( (sum_k A[m,k]*Bt[n,k] + bias[n]) * scale )
// A: [M,K] bf16 (stride lda), Bt: [N,K] bf16 (stride ldb)
// Tile 128 x BN, BK=32. BN=128 -> 4 waves, BN=256 -> 8 waves.
// LDS slot-swizzle (both-sides, rule #21): 16B chunk (row r, slot s) holds
// global k-chunk s^((r>>1)&3); fragment ds_read applies same XOR -> conflict-free.
// flags: bit0 = bf16 out, bit1 = relu.  grid = (N/BN, M/128, Z).
// ---------------------------------------------------------------------------
template <int BN>
__global__ __launch_bounds__(BN == 256 ? 512 : 256)
void gemm_bt(const bf16* __restrict__ A, const bf16* __restrict__ B,
             void* __restrict__ C, const float* __restrict__ bias,
             int K, int lda, int ldb, int ldc,
             long sAz, long sBz, long sCz,
             float scale, int flags) {
  constexpr int NW = BN / 32;               // 4 or 8 waves
  constexpr int WC = NW / 2;                // wave cols (2 or 4)
  constexpr int AG = 512 / (NW * 64);       // A staging chunks per lane
  constexpr int BG = (BN * 4) / (NW * 64);  // B staging chunks per lane

  __shared__ __align__(16) bf16 As[2][128 * 32];
  __shared__ __align__(16) bf16 Bs[2][BN * 32];

  const int tid  = threadIdx.x;
  const int lane = tid & 63;
  const int w    = tid >> 6;
  const int wr   = w / WC, wc = w % WC;
  const long z   = blockIdx.z;

  const bf16* Ab = A + (long)blockIdx.y * 128 * lda + z * sAz;
  const bf16* Bb = B + (long)blockIdx.x * BN * ldb + z * sBz;

  // per-lane staging sources (inverse-swizzled global slot; LDS stays linear)
  const bf16* aSrc[AG];
#pragma unroll
  for (int g = 0; g < AG; g++) {
    const int c = (w * AG + g) * 64 + lane;
    const int r = c >> 2, sl = c & 3;
    aSrc[g] = Ab + (long)r * lda + ((sl ^ ((r >> 1) & 3)) << 3);
  }
  const bf16* bSrc[BG];
#pragma unroll
  for (int g = 0; g < BG; g++) {
    const int c = (w * BG + g) * 64 + lane;
    const int r = c >> 2, sl = c & 3;
    bSrc[g] = Bb + (long)r * ldb + ((sl ^ ((r >> 1) & 3)) << 3);
  }

  f32x4 acc[4][4] = {};
  const int r16 = lane & 15, kq = lane >> 4;
  const int so = ((kq ^ ((r16 >> 1) & 3)) << 3);  // swizzled ds_read slot

  auto stage = [&](int buf, int k0) {
#pragma unroll
    for (int g = 0; g < AG; g++)
      async_lds16(aSrc[g] + k0, &As[buf][(w * AG + g) * 512]);
#pragma unroll
    for (int g = 0; g < BG; g++)
      async_lds16(bSrc[g] + k0, &Bs[buf][(w * BG + g) * 512]);
  };
  auto compute = [&](int buf) {
    bf16x8 areg[4], breg[4];
#pragma unroll
    for (int i = 0; i < 4; i++)
      areg[i] = *(const bf16x8*)&As[buf][(wr * 64 + i * 16 + r16) * 32 + so];
#pragma unroll
    for (int j = 0; j < 4; j++)
      breg[j] = *(const bf16x8*)&Bs[buf][(wc * 64 + j * 16 + r16) * 32 + so];
    __builtin_amdgcn_s_setprio(1);
#pragma unroll
    for (int i = 0; i < 4; i++)
#pragma unroll
      for (int j = 0; j < 4; j++)
        acc[i][j] = __builtin_amdgcn_mfma_f32_16x16x32_bf16(areg[i], breg[j], acc[i][j], 0, 0, 0);
    __builtin_amdgcn_s_setprio(0);
  };

  stage(0, 0);
  __syncthreads();
  int cur = 0;
  const int nt = K >> 5;
  for (int t = 1; t < nt; ++t) {
    stage(cur ^ 1, t * 32);                 // issue next tile's loads
    __builtin_amdgcn_sched_barrier(0);      // keep issue before ds_read/MFMA
    compute(cur);                           // overlap with loads in flight
    __syncthreads();                        // vmcnt(0)+barrier: next tile ready
    cur ^= 1;
  }
  compute(cur);

  // epilogue: C frag layout col = lane&15, row = (lane>>4)*4 + reg   [m89]
  const long rowBase = (long)blockIdx.y * 128 + wr * 64;
  const int  colBase = blockIdx.x * BN + wc * 64;
  float* Cf = (float*)C;
  bf16*  Cb = (bf16*)C;
  const int rq = lane >> 4;
#pragma unroll
  for (int i = 0; i < 4; i++) {
#pragma unroll
    for (int j = 0; j < 4; j++) {
      const int col = colBase + j * 16 + r16;
      const float bv = bias ? bias[col] : 0.f;
#pragma unroll
      for (int rg = 0; rg < 4; rg++) {
        const long row = rowBase + i * 16 + rq * 4 + rg;
        float y = (acc[i][j][rg] + bv) * scale;
        if (flags & 2) y = fmaxf(y, 0.f);
        const long idx = z * sCz + row * (long)ldc + col;
        if (flags & 1) Cb[idx] = (bf16)y;
        else           Cf[idx] = y;
      }
    }
  }
}

// ---------------------------------------------------------------------------
// f32 [K][N] -> bf16 [N][K] transpose with scale (dims multiples of 32)
// ---------------------------------------------------------------------------
__global__ void transpose_w_kernel(const float* __restrict__ in, bf16* __restrict__ out,
                                   int K, int N, float scale) {
  __shared__ float t[32][33];
  const int n0 = blockIdx.x * 32, k0 = blockIdx.y * 32;
  const int tx = threadIdx.x, ty = threadIdx.y;
#pragma unroll
  for (int i = ty; i < 32; i += 8)
    t[i][tx] = in[(long)(k0 + i) * N + n0 + tx];
  __syncthreads();
#pragma unroll
  for (int i = ty; i < 32; i += 8)
    out[(long)(n0 + i) * K + k0 + tx] = (bf16)(t[tx][i] * scale);
}

// concat+scale biases: [bq*0.125 | bk | bv | bqv*0.17678]  (1792 f32)
__global__ void build_bias_kernel(const float* bq, const float* bk,
                                  const float* bv, const float* bqv,
                                  float* __restrict__ out) {
  const int i = blockIdx.x * 256 + threadIdx.x;
  float v;
  if (i < 512)       v = bq[i] * 0.125f;
  else if (i < 1024) v = bk[i - 512];
  else if (i < 1536) v = bv[i - 1024];
  else               v = bqv[i - 1536] * 0.17677669529663687f;
  out[i] = v;
}

// v (cols 1024..1535 of qkv, row stride 1792) -> vT bf16 [B][512][S]
__global__ void transpose_v_kernel(const bf16* __restrict__ qkv, bf16* __restrict__ vT) {
  __shared__ bf16 t[32][33];
  const int s0 = blockIdx.x * 32, c0 = blockIdx.y * 32, b = blockIdx.z;
  const int tx = threadIdx.x, ty = threadIdx.y;
#pragma unroll
  for (int i = ty; i < 32; i += 8)
    t[i][tx] = qkv[((long)b * SEQ + s0 + i) * QKVW + 1024 + c0 + tx];
  __syncthreads();
#pragma unroll
  for (int i = ty; i < 32; i += 8)
    vT[(long)b * 512 * SEQ + (long)(c0 + i) * SEQ + s0 + tx] = t[tx][i];
}

// x f32 [S][B][D] -> xb bf16 [B*S][D]  (token = b*S+s)
__global__ __launch_bounds__(256)
void convert_x_kernel(const float* __restrict__ x, bf16* __restrict__ xb) {
  const long i0 = ((long)blockIdx.x * 256 + threadIdx.x) * 8;
  const int t = (int)(i0 >> 9), d = (int)(i0 & 511);
  const int b = t >> 11, s = t & 2047;
  const float* src = x + ((long)(s * BAT + b) << 9) + d;
  const float4 f0 = *(const float4*)(src);
  const float4 f1 = *(const float4*)(src + 4);
  bf16x8 o;
  o[0] = (bf16)f0.x; o[1] = (bf16)f0.y; o[2] = (bf16)f0.z; o[3] = (bf16)f0.w;
  o[4] = (bf16)f1.x; o[5] = (bf16)f1.y; o[6] = (bf16)f1.z; o[7] = (bf16)f1.w;
  *(bf16x8*)&xb[i0] = o;
}

// in-place row softmax over 2048 bf16 elements; one block per row
__global__ __launch_bounds__(256)
void softmax_kernel(bf16* __restrict__ p) {
  __shared__ float red[8];
  bf16* pr = p + (long)blockIdx.x * 2048;
  const int tid = threadIdx.x, lane = tid & 63, wid = tid >> 6;
  bf16x8 v = *(bf16x8*)&pr[tid * 8];
  float f[8];
#pragma unroll
  for (int j = 0; j < 8; j++) f[j] = (float)v[j];
  float m = f[0];
#pragma unroll
  for (int j = 1; j < 8; j++) m = fmaxf(m, f[j]);
  for (int o = 1; o < 64; o <<= 1) m = fmaxf(m, __shfl_xor(m, o));
  if (lane == 0) red[wid] = m;
  __syncthreads();
  m = fmaxf(fmaxf(red[0], red[1]), fmaxf(red[2], red[3]));
  float sum = 0.f;
#pragma unroll
  for (int j = 0; j < 8; j++) { f[j] = __expf(f[j] - m); sum += f[j]; }
  for (int o = 1; o < 64; o <<= 1) sum += __shfl_xor(sum, o);
  if (lane == 0) red[4 + wid] = sum;
  __syncthreads();
  sum = red[4] + red[5] + red[6] + red[7];
  const float inv = 1.f / sum;
#pragma unroll
  for (int j = 0; j < 8; j++) v[j] = (bf16)(f[j] * inv);
  *(bf16x8*)&pr[tid * 8] = v;
}

// ---------------------------------------------------------------------------
// Stage-2 composition: one wave per (b,h,s).
// logit_r = sum_d out[r,d] * wq[d] + (bkv.qv)  with wq = Wkv @ qv
// o[d] = sum_r softmax_r(logit) * out[r,d]
// outbuf: [nB][H][S][512] (strideB elems per b); qv at row stride qvStride.
// ---------------------------------------------------------------------------
__global__ __launch_bounds__(256)
void stage2_kernel(const bf16* __restrict__ outbuf, long strideB,
                   const bf16* __restrict__ qvb, int qvStride,
                   const float* __restrict__ Wkv,
                   const float* __restrict__ bkv,
                   bf16* __restrict__ attn,
                   int tokenBase) {
  const int lane = threadIdx.x & 63, wid = threadIdx.x >> 6;
  const int g = blockIdx.x * 4 + wid;
  const int s = g & 2047, h = (g >> 11) & 7, b = g >> 14;
  const int token = tokenBase + b * SEQ + s;

  const bf16* qv = qvb + (long)token * qvStride + h * 32;
  const float* wrow = Wkv + lane * 32;
  float wq = 0.f, cb = 0.f;
#pragma unroll 8
  for (int q = 0; q < 32; q++) {
    const float qf = (float)qv[q];
    wq += wrow[q] * qf;
    cb += bkv[q] * qf;
  }

  const bf16* orow = outbuf + b * strideB + ((long)(h << 11) + s) * 512;
  float of[8], lg[8];
#pragma unroll
  for (int r = 0; r < 8; r++) {
    of[r] = (float)orow[r * 64 + lane];
    float p = of[r] * wq;
    for (int o = 1; o < 64; o <<= 1) p += __shfl_xor(p, o);
    lg[r] = p + cb;
  }
  float m = lg[0];
#pragma unroll
  for (int r = 1; r < 8; r++) m = fmaxf(m, lg[r]);
  float e[8], sum = 0.f;
#pragma unroll
  for (int r = 0; r < 8; r++) { e[r] = __expf(lg[r] - m); sum += e[r]; }
  const float inv = 1.f / sum;
  float o = 0.f;
#pragma unroll
  for (int r = 0; r < 8; r++) o += e[r] * inv * of[r];
  attn[(long)token * 512 + h * 64 + lane] = (bf16)o;
}

// ---------------------------------------------------------------------------
// LayerNorm over D=512 per token. a: token-major GEMM out; bres: residual.
// bresT: residual indexed in [S][B][D] layout; outT: write d_out in [S][B][D].
// ---------------------------------------------------------------------------
__global__ __launch_bounds__(256)
void ln_kernel(const float* __restrict__ a, const float* __restrict__ bres, int bresT,
               const float* __restrict__ g, const float* __restrict__ be,
               float* __restrict__ outF, bf16* __restrict__ outB, int outT) {
  __shared__ float red[8];
  const int t = blockIdx.x, tid = threadIdx.x;
  const int b = t >> 11, s = t & 2047;
  const long ti = (long)t * 512;
  const long xi = (long)(s * BAT + b) * 512;
  const long ri = bresT ? xi : ti;
  const float v0 = a[ti + tid]       + bres[ri + tid];
  const float v1 = a[ti + 256 + tid] + bres[ri + 256 + tid];
  float sum = v0 + v1, sq = v0 * v0 + v1 * v1;
  const int lane = tid & 63, wid = tid >> 6;
  for (int o = 1; o < 64; o <<= 1) { sum += __shfl_xor(sum, o); sq += __shfl_xor(sq, o); }
  if (lane == 0) { red[wid] = sum; red[4 + wid] = sq; }
  __syncthreads();
  sum = red[0] + red[1] + red[2] + red[3];
  sq  = red[4] + red[5] + red[6] + red[7];
  const float mu = sum * (1.f / 512.f);
  const float var = sq * (1.f / 512.f) - mu * mu;
  const float rs = rsqrtf(var + 1e-5f);
  const float y0 = (v0 - mu) * rs * g[tid] + be[tid];
  const float y1 = (v1 - mu) * rs * g[tid + 256] + be[tid + 256];
  const long oi = outT ? xi : ti;
  if (outF) { outF[oi + tid] = y0; outF[oi + 256 + tid] = y1; }
  if (outB) { outB[ti + tid] = (bf16)y0; outB[ti + 256 + tid] = (bf16)y1; }
}

// ---------------------------------------------------------------------------
extern "C" void kernel_launch(void* const* d_in, const int* in_sizes, int n_in,
                              void* d_out, int out_size, void* d_ws, size_t ws_size,
                              hipStream_t stream) {
  const float* x   = (const float*)d_in[0];
  const float* Wq  = (const float*)d_in[1];
  const float* bq  = (const float*)d_in[2];
  const float* Wk  = (const float*)d_in[3];
  const float* bk  = (const float*)d_in[4];
  const float* Wv  = (const float*)d_in[5];
  const float* bv  = (const float*)d_in[6];
  const float* Wqv = (const float*)d_in[7];
  const float* bqv = (const float*)d_in[8];
  const float* Wkv = (const float*)d_in[9];
  const float* bkv = (const float*)d_in[10];
  const float* Wf  = (const float*)d_in[11];
  const float* bfc = (const float*)d_in[12];
  const float* W1  = (const float*)d_in[13];
  const float* b1  = (const float*)d_in[14];
  const float* W2  = (const float*)d_in[15];
  const float* b2  = (const float*)d_in[16];
  const float* g1  = (const float*)d_in[17];
  const float* be1 = (const float*)d_in[18];
  const float* g2  = (const float*)d_in[19];
  const float* be2 = (const float*)d_in[20];

  char* ws = (char*)d_ws;
  size_t off = 0;
  auto alloc = [&](size_t bytes) -> void* {
    void* p = ws + off;
    off += (bytes + 1023) & ~(size_t)1023;
    return p;
  };
  bf16*  xb    = (bf16*)alloc((size_t)NTOK * 512 * 2);
  bf16*  qkv   = (bf16*)alloc((size_t)NTOK * QKVW * 2);   // [q|k|v|qv]
  bf16*  vT    = (bf16*)alloc((size_t)BAT * 512 * SEQ * 2);
  bf16*  wtPk  = (bf16*)alloc((size_t)QKVW * 512 * 2);    // packed WqT|WkT|WvT|WqvT
  bf16*  WfT   = (bf16*)alloc(512 * 512 * 2);
  bf16*  W1T   = (bf16*)alloc((size_t)2048 * 512 * 2);
  bf16*  W2T   = (bf16*)alloc((size_t)512 * 2048 * 2);
  float* bcat  = (float*)alloc(QKVW * 4);
  bf16*  attn  = (bf16*)alloc((size_t)NTOK * 512 * 2);
  float* wfo   = (float*)alloc((size_t)NTOK * 512 * 4);   // aliased by ffn2 out
  float* ln1f  = (float*)alloc((size_t)NTOK * 512 * 4);
  bf16*  ln1b  = (bf16*)alloc((size_t)NTOK * 512 * 2);

  const size_t outbA = (size_t)BAT * NH * SEQ * 512 * 2;   // 64 MB
  const size_t pbufA = (size_t)BAT * NH * SEQ * SEQ * 2;   // 256 MB
  const size_t outbB = (size_t)NH * SEQ * 512 * 2;         // 16 MB
  const size_t pbufB = (size_t)NH * SEQ * SEQ * 2;         // 64 MB
  const bool bigP = ws_size >= off + outbA + pbufA + 4096;
  bf16* outb = (bf16*)alloc(bigP ? outbA : outbB);
  bf16* pbuf = (bf16*)alloc(bigP ? pbufA : pbufB);
  bf16* ffn1 = pbuf;          // 32 MB needed, fits both paths
  float* ffn2 = wfo;

  const dim3 tb(32, 8);
  // packed projection weights (scales baked in)
  transpose_w_kernel<<<dim3(16, 16), tb, 0, stream>>>(Wq,  wtPk,              512, 512, 0.125f);
  transpose_w_kernel<<<dim3(16, 16), tb, 0, stream>>>(Wk,  wtPk + 512  * 512, 512, 512, 1.f);
  transpose_w_kernel<<<dim3(16, 16), tb, 0, stream>>>(Wv,  wtPk + 1024 * 512, 512, 512, 1.f);
  transpose_w_kernel<<<dim3(8, 16),  tb, 0, stream>>>(Wqv, wtPk + 1536 * 512, 512, 256, 0.17677669529663687f);
  transpose_w_kernel<<<dim3(16, 16), tb, 0, stream>>>(Wf,  WfT, 512, 512, 1.f);
  transpose_w_kernel<<<dim3(64, 16), tb, 0, stream>>>(W1,  W1T, 512, 2048, 1.f);
  transpose_w_kernel<<<dim3(16, 64), tb, 0, stream>>>(W2,  W2T, 2048, 512, 1.f);
  build_bias_kernel<<<7, 256, 0, stream>>>(bq, bk, bv, bqv, bcat);
  convert_x_kernel<<<2048, 256, 0, stream>>>(x, xb);

  // fused q|k|v|qv projection: [8192,512] @ [1792,512]^T -> [8192,1792]
  gemm_bt<256><<<dim3(7, 64, 1), 512, 0, stream>>>(xb, wtPk, qkv, bcat,
      512, 512, 512, QKVW, 0, 0, 0, 1.f, 1);

  transpose_v_kernel<<<dim3(64, 16, 4), tb, 0, stream>>>(qkv, vT);

  const long sPb = (long)NH * SEQ * SEQ;       // P elems per batch
  const long sOb = (long)NH * SEQ * 512;       // outb elems per batch
  if (bigP) {
    for (int b = 0; b < BAT; b++) {
      const bf16* qB = qkv + (size_t)b * SEQ * QKVW;
      gemm_bt<256><<<dim3(8, 16, 8), 512, 0, stream>>>(qB, qB + 512, pbuf + (size_t)b * sPb,
          nullptr, 64, QKVW, QKVW, 2048, 64, 64, (long)SEQ * SEQ, 1.f, 1);
    }
    softmax_kernel<<<BAT * NH * SEQ, 256, 0, stream>>>(pbuf);
    // PV all batches: [16384,2048]@[2048,512] per z=batch
    gemm_bt<128><<<dim3(4, 128, 4), 256, 0, stream>>>(pbuf, vT, outb, nullptr,
        2048, 2048, 2048, 512, sPb, (long)512 * SEQ, sOb, 1.f, 1);
    stage2_kernel<<<BAT * NH * SEQ / 4, 256, 0, stream>>>(outb, sOb, qkv + 1536, QKVW,
        Wkv, bkv, attn, 0);
  } else {
    for (int b = 0; b < BAT; b++) {
      const bf16* qB = qkv + (size_t)b * SEQ * QKVW;
      gemm_bt<256><<<dim3(8, 16, 8), 512, 0, stream>>>(qB, qB + 512, pbuf, nullptr,
          64, QKVW, QKVW, 2048, 64, 64, (long)SEQ * SEQ, 1.f, 1);
      softmax_kernel<<<NH * SEQ, 256, 0, stream>>>(pbuf);
      gemm_bt<128><<<dim3(4, 128, 1), 256, 0, stream>>>(pbuf, vT + (size_t)b * 512 * SEQ,
          outb, nullptr, 2048, 2048, 2048, 512, 0, 0, 0, 1.f, 1);
      stage2_kernel<<<NH * SEQ / 4, 256, 0, stream>>>(outb, 0, qkv + 1536, QKVW,
          Wkv, bkv, attn, b * SEQ);
    }
  }

  gemm_bt<128><<<dim3(4, 64, 1), 256, 0, stream>>>(attn, WfT, wfo, bfc,
      512, 512, 512, 512, 0, 0, 0, 1.f, 0);
  ln_kernel<<<NTOK, 256, 0, stream>>>(wfo, x, 1, g1, be1, ln1f, ln1b, 0);
  gemm_bt<256><<<dim3(8, 64, 1), 512, 0, stream>>>(ln1b, W1T, ffn1, b1,
      512, 512, 512, 2048, 0, 0, 0, 1.f, 1 | 2);
  gemm_bt<128><<<dim3(4, 64, 1), 256, 0, stream>>>(ffn1, W2T, ffn2, b2,
      2048, 2048, 2048, 512, 0, 0, 0, 1.f, 0);
  ln_kernel<<<NTOK, 256, 0, stream>>>(ffn2, ln1f, 0, g2, be2, (float*)d_out, nullptr, 1);
}

// Round 4
// 659.571 us; speedup vs baseline: 1.1547x; 1.0428x over previous
//
#include <hip/hip_runtime.h>
#include <hip/hip_bf16.h>

typedef __bf16 bf16;
typedef bf16 bf16x8 __attribute__((ext_vector_type(8)));
typedef float f32x4 __attribute__((ext_vector_type(4)));

constexpr int SEQ  = 2048;
constexpr int BAT  = 4;
constexpr int NH   = 8;
constexpr int NTOK = SEQ * BAT;   // 8192
constexpr int QKVW = 1792;        // fused projection width: 512+512+512+256

// ---------------------------------------------------------------------------
// async global->LDS 16B copy (wave-uniform LDS base + lane*16)
// ---------------------------------------------------------------------------
__device__ inline void async_lds16(const void* g, void* l) {
  __builtin_amdgcn_global_load_lds(
      (__attribute__((address_space(1))) void*)(g),
      (__attribute__((address_space(3))) void*)(l), 16, 0, 0);
}

// ---------------------------------------------------------------------------
// bf16 MFMA GEMM, 128x128 tile, BK=32, 4 waves, 3-deep counted-vmcnt pipeline
// (T3+T4) + T1 XCD-chunked block swizzle + T5 setprio.
//   C[m,n] = act( (sum_k A[m,k]*Bt[n,k] + bias[n]) * scale )
// A: [M,K] bf16 (stride lda), Bt: [N,K] bf16 (stride ldb)
// LDS slot-swizzle (both-sides, rule #21): 16B chunk (row r, slot s) holds
// global k-chunk s^((r>>1)&3); fragment ds_read applies same XOR.
// flags: bit0 = bf16 out, bit1 = relu.  grid = (N/128, M/128, Z).
// ---------------------------------------------------------------------------
__global__ __launch_bounds__(256)
void gemm_bt(const bf16* __restrict__ A, const bf16* __restrict__ B,
             void* __restrict__ C, const float* __restrict__ bias,
             int K, int lda, int ldb, int ldc,
             long sAz, long sBz, long sCz,
             float scale, int flags) {
  constexpr int LPT = 4;                    // global_load_lds per thread per tile
  __shared__ __align__(16) bf16 As[3][128 * 32];
  __shared__ __align__(16) bf16 Bs[3][128 * 32];

  const int tid  = threadIdx.x;
  const int lane = tid & 63;
  const int w    = tid >> 6;
  const int wr   = w >> 1, wc = w & 1;

  // ---- T1: bijective XCD-chunked swizzle (m204) over the flat grid ----
  const int gx = gridDim.x, gy = gridDim.y;
  const int nwg = gx * gy * gridDim.z;
  const int flat = blockIdx.x + gx * (blockIdx.y + gy * blockIdx.z);
  const int q = nwg >> 3, r = nwg & 7;
  const int xcd = flat & 7, pos = flat >> 3;
  int swz = (xcd < r ? xcd * (q + 1) : r * (q + 1) + (xcd - r) * q) + pos;
  const int bx = swz % gx; swz /= gx;
  const int by = swz % gy;
  const long z = swz / gy;

  const bf16* Ab = A + (long)by * 128 * lda + z * sAz;
  const bf16* Bb = B + (long)bx * 128 * ldb + z * sBz;

  // per-lane staging sources (inverse-swizzled global slot; LDS stays linear)
  const bf16* aSrc[2];
  const bf16* bSrc[2];
#pragma unroll
  for (int g = 0; g < 2; g++) {
    const int c = (w * 2 + g) * 64 + lane;
    const int rr = c >> 2, sl = c & 3;
    aSrc[g] = Ab + (long)rr * lda + ((sl ^ ((rr >> 1) & 3)) << 3);
    bSrc[g] = Bb + (long)rr * ldb + ((sl ^ ((rr >> 1) & 3)) << 3);
  }

  f32x4 acc[4][4] = {};
  const int r16 = lane & 15, kq = lane >> 4;
  const int so = ((kq ^ ((r16 >> 1) & 3)) << 3);  // swizzled ds_read slot

  auto stage = [&](int buf, int k0) {
#pragma unroll
    for (int g = 0; g < 2; g++)
      async_lds16(aSrc[g] + k0, &As[buf][(w * 2 + g) * 512]);
#pragma unroll
    for (int g = 0; g < 2; g++)
      async_lds16(bSrc[g] + k0, &Bs[buf][(w * 2 + g) * 512]);
  };
  bf16x8 areg[4], breg[4];
  auto loadfrags = [&](int buf) {
#pragma unroll
    for (int i = 0; i < 4; i++)
      areg[i] = *(const bf16x8*)&As[buf][(wr * 64 + i * 16 + r16) * 32 + so];
#pragma unroll
    for (int j = 0; j < 4; j++)
      breg[j] = *(const bf16x8*)&Bs[buf][(wc * 64 + j * 16 + r16) * 32 + so];
  };
  auto domfma = [&]() {
    __builtin_amdgcn_s_setprio(1);
#pragma unroll
    for (int i = 0; i < 4; i++)
#pragma unroll
      for (int j = 0; j < 4; j++)
        acc[i][j] = __builtin_amdgcn_mfma_f32_16x16x32_bf16(areg[i], breg[j], acc[i][j], 0, 0, 0);
    __builtin_amdgcn_s_setprio(0);
  };

  const int nt = K >> 5;
  stage(0, 0);
  if (nt > 1) stage(1, 32);

  int cs = 2;  // next buffer to stage
  int cc = 0;  // buffer to compute
  for (int t = 0; t + 2 < nt; ++t) {
    stage(cs, (t + 2) * 32);
    asm volatile("s_waitcnt vmcnt(%0)" : : "n"(2 * LPT) : "memory");
    __builtin_amdgcn_s_barrier();            // tile t visible to all waves
    loadfrags(cc);
    asm volatile("s_waitcnt lgkmcnt(0)" : : : "memory");
    __builtin_amdgcn_sched_barrier(0);       // rule #18
    __builtin_amdgcn_s_barrier();            // all reads done -> buf reusable
    domfma();
    if (++cs == 3) cs = 0;
    if (++cc == 3) cc = 0;
  }
  if (nt >= 2) {                             // tile nt-2: one stage still in flight
    asm volatile("s_waitcnt vmcnt(%0)" : : "n"(LPT) : "memory");
    __builtin_amdgcn_s_barrier();
    loadfrags(cc);
    asm volatile("s_waitcnt lgkmcnt(0)" : : : "memory");
    __builtin_amdgcn_sched_barrier(0);
    domfma();
    if (++cc == 3) cc = 0;
  }
  asm volatile("s_waitcnt vmcnt(0)" : : : "memory");   // last tile
  __builtin_amdgcn_s_barrier();
  loadfrags(cc);
  domfma();

  // epilogue: C frag layout col = lane&15, row = (lane>>4)*4 + reg   [m89]
  const long rowBase = (long)by * 128 + wr * 64;
  const int  colBase = bx * 128 + wc * 64;
  float* Cf = (float*)C;
  bf16*  Cb = (bf16*)C;
  const int rq = lane >> 4;
#pragma unroll
  for (int i = 0; i < 4; i++) {
#pragma unroll
    for (int j = 0; j < 4; j++) {
      const int col = colBase + j * 16 + r16;
      const float bv = bias ? bias[col] : 0.f;
#pragma unroll
      for (int rg = 0; rg < 4; rg++) {
        const long row = rowBase + i * 16 + rq * 4 + rg;
        float y = (acc[i][j][rg] + bv) * scale;
        if (flags & 2) y = fmaxf(y, 0.f);
        const long idx = z * sCz + row * (long)ldc + col;
        if (flags & 1) Cb[idx] = (bf16)y;
        else           Cf[idx] = y;
      }
    }
  }
}

// ---------------------------------------------------------------------------
// f32 [K][N] -> bf16 [N][K] transpose with scale (dims multiples of 32)
// ---------------------------------------------------------------------------
__global__ void transpose_w_kernel(const float* __restrict__ in, bf16* __restrict__ out,
                                   int K, int N, float scale) {
  __shared__ float t[32][33];
  const int n0 = blockIdx.x * 32, k0 = blockIdx.y * 32;
  const int tx = threadIdx.x, ty = threadIdx.y;
#pragma unroll
  for (int i = ty; i < 32; i += 8)
    t[i][tx] = in[(long)(k0 + i) * N + n0 + tx];
  __syncthreads();
#pragma unroll
  for (int i = ty; i < 32; i += 8)
    out[(long)(n0 + i) * K + k0 + tx] = (bf16)(t[tx][i] * scale);
}

// concat+scale biases: [bq*0.125 | bk | bv | bqv*0.17678]  (1792 f32)
__global__ void build_bias_kernel(const float* bq, const float* bk,
                                  const float* bv, const float* bqv,
                                  float* __restrict__ out) {
  const int i = blockIdx.x * 256 + threadIdx.x;
  float v;
  if (i < 512)       v = bq[i] * 0.125f;
  else if (i < 1024) v = bk[i - 512];
  else if (i < 1536) v = bv[i - 1024];
  else               v = bqv[i - 1536] * 0.17677669529663687f;
  out[i] = v;
}

// v (cols 1024..1535 of qkv, row stride 1792) -> vT bf16 [B][512][S]
__global__ void transpose_v_kernel(const bf16* __restrict__ qkv, bf16* __restrict__ vT) {
  __shared__ bf16 t[32][33];
  const int s0 = blockIdx.x * 32, c0 = blockIdx.y * 32, b = blockIdx.z;
  const int tx = threadIdx.x, ty = threadIdx.y;
#pragma unroll
  for (int i = ty; i < 32; i += 8)
    t[i][tx] = qkv[((long)b * SEQ + s0 + i) * QKVW + 1024 + c0 + tx];
  __syncthreads();
#pragma unroll
  for (int i = ty; i < 32; i += 8)
    vT[(long)b * 512 * SEQ + (long)(c0 + i) * SEQ + s0 + tx] = t[tx][i];
}

// x f32 [S][B][D] -> xb bf16 [B*S][D]  (token = b*S+s)
__global__ __launch_bounds__(256)
void convert_x_kernel(const float* __restrict__ x, bf16* __restrict__ xb) {
  const long i0 = ((long)blockIdx.x * 256 + threadIdx.x) * 8;
  const int t = (int)(i0 >> 9), d = (int)(i0 & 511);
  const int b = t >> 11, s = t & 2047;
  const float* src = x + ((long)(s * BAT + b) << 9) + d;
  const float4 f0 = *(const float4*)(src);
  const float4 f1 = *(const float4*)(src + 4);
  bf16x8 o;
  o[0] = (bf16)f0.x; o[1] = (bf16)f0.y; o[2] = (bf16)f0.z; o[3] = (bf16)f0.w;
  o[4] = (bf16)f1.x; o[5] = (bf16)f1.y; o[6] = (bf16)f1.z; o[7] = (bf16)f1.w;
  *(bf16x8*)&xb[i0] = o;
}

// in-place row softmax over 2048 bf16 elements; one block per row
__global__ __launch_bounds__(256)
void softmax_kernel(bf16* __restrict__ p) {
  __shared__ float red[8];
  bf16* pr = p + (long)blockIdx.x * 2048;
  const int tid = threadIdx.x, lane = tid & 63, wid = tid >> 6;
  bf16x8 v = *(bf16x8*)&pr[tid * 8];
  float f[8];
#pragma unroll
  for (int j = 0; j < 8; j++) f[j] = (float)v[j];
  float m = f[0];
#pragma unroll
  for (int j = 1; j < 8; j++) m = fmaxf(m, f[j]);
  for (int o = 1; o < 64; o <<= 1) m = fmaxf(m, __shfl_xor(m, o));
  if (lane == 0) red[wid] = m;
  __syncthreads();
  m = fmaxf(fmaxf(red[0], red[1]), fmaxf(red[2], red[3]));
  float sum = 0.f;
#pragma unroll
  for (int j = 0; j < 8; j++) { f[j] = __expf(f[j] - m); sum += f[j]; }
  for (int o = 1; o < 64; o <<= 1) sum += __shfl_xor(sum, o);
  if (lane == 0) red[4 + wid] = sum;
  __syncthreads();
  sum = red[4] + red[5] + red[6] + red[7];
  const float inv = 1.f / sum;
#pragma unroll
  for (int j = 0; j < 8; j++) v[j] = (bf16)(f[j] * inv);
  *(bf16x8*)&pr[tid * 8] = v;
}

// ---------------------------------------------------------------------------
// Stage-2 composition: one wave per (b,h,s).
// logit_r = sum_d out[r,d] * wq[d] + (bkv.qv)  with wq = Wkv @ qv
// o[d] = sum_r softmax_r(logit) * out[r,d]
// outbuf: [nB][H][S][512] (strideB elems per b); qv at row stride qvStride.
// ---------------------------------------------------------------------------
__global__ __launch_bounds__(256)
void stage2_kernel(const bf16* __restrict__ outbuf, long strideB,
                   const bf16* __restrict__ qvb, int qvStride,
                   const float* __restrict__ Wkv,
                   const float* __restrict__ bkv,
                   bf16* __restrict__ attn,
                   int tokenBase) {
  const int lane = threadIdx.x & 63, wid = threadIdx.x >> 6;
  const int g = blockIdx.x * 4 + wid;
  const int s = g & 2047, h = (g >> 11) & 7, b = g >> 14;
  const int token = tokenBase + b * SEQ + s;

  const bf16* qv = qvb + (long)token * qvStride + h * 32;
  const float* wrow = Wkv + lane * 32;
  float wq = 0.f, cb = 0.f;
#pragma unroll 8
  for (int q = 0; q < 32; q++) {
    const float qf = (float)qv[q];
    wq += wrow[q] * qf;
    cb += bkv[q] * qf;
  }

  const bf16* orow = outbuf + b * strideB + ((long)(h << 11) + s) * 512;
  float of[8], lg[8];
#pragma unroll
  for (int r = 0; r < 8; r++) {
    of[r] = (float)orow[r * 64 + lane];
    float p = of[r] * wq;
    for (int o = 1; o < 64; o <<= 1) p += __shfl_xor(p, o);
    lg[r] = p + cb;
  }
  float m = lg[0];
#pragma unroll
  for (int r = 1; r < 8; r++) m = fmaxf(m, lg[r]);
  float e[8], sum = 0.f;
#pragma unroll
  for (int r = 0; r < 8; r++) { e[r] = __expf(lg[r] - m); sum += e[r]; }
  const float inv = 1.f / sum;
  float o = 0.f;
#pragma unroll
  for (int r = 0; r < 8; r++) o += e[r] * inv * of[r];
  attn[(long)token * 512 + h * 64 + lane] = (bf16)o;
}

// ---------------------------------------------------------------------------
// LayerNorm over D=512 per token. a: token-major GEMM out; bres: residual.
// bresT: residual indexed in [S][B][D] layout; outT: write d_out in [S][B][D].
// ---------------------------------------------------------------------------
__global__ __launch_bounds__(256)
void ln_kernel(const float* __restrict__ a, const float* __restrict__ bres, int bresT,
               const float* __restrict__ g, const float* __restrict__ be,
               float* __restrict__ outF, bf16* __restrict__ outB, int outT) {
  __shared__ float red[8];
  const int t = blockIdx.x, tid = threadIdx.x;
  const int b = t >> 11, s = t & 2047;
  const long ti = (long)t * 512;
  const long xi = (long)(s * BAT + b) * 512;
  const long ri = bresT ? xi : ti;
  const float v0 = a[ti + tid]       + bres[ri + tid];
  const float v1 = a[ti + 256 + tid] + bres[ri + 256 + tid];
  float sum = v0 + v1, sq = v0 * v0 + v1 * v1;
  const int lane = tid & 63, wid = tid >> 6;
  for (int o = 1; o < 64; o <<= 1) { sum += __shfl_xor(sum, o); sq += __shfl_xor(sq, o); }
  if (lane == 0) { red[wid] = sum; red[4 + wid] = sq; }
  __syncthreads();
  sum = red[0] + red[1] + red[2] + red[3];
  sq  = red[4] + red[5] + red[6] + red[7];
  const float mu = sum * (1.f / 512.f);
  const float var = sq * (1.f / 512.f) - mu * mu;
  const float rs = rsqrtf(var + 1e-5f);
  const float y0 = (v0 - mu) * rs * g[tid] + be[tid];
  const float y1 = (v1 - mu) * rs * g[tid + 256] + be[tid + 256];
  const long oi = outT ? xi : ti;
  if (outF) { outF[oi + tid] = y0; outF[oi + 256 + tid] = y1; }
  if (outB) { outB[ti + tid] = (bf16)y0; outB[ti + 256 + tid] = (bf16)y1; }
}

// ---------------------------------------------------------------------------
extern "C" void kernel_launch(void* const* d_in, const int* in_sizes, int n_in,
                              void* d_out, int out_size, void* d_ws, size_t ws_size,
                              hipStream_t stream) {
  const float* x   = (const float*)d_in[0];
  const float* Wq  = (const float*)d_in[1];
  const float* bq  = (const float*)d_in[2];
  const float* Wk  = (const float*)d_in[3];
  const float* bk  = (const float*)d_in[4];
  const float* Wv  = (const float*)d_in[5];
  const float* bv  = (const float*)d_in[6];
  const float* Wqv = (const float*)d_in[7];
  const float* bqv = (const float*)d_in[8];
  const float* Wkv = (const float*)d_in[9];
  const float* bkv = (const float*)d_in[10];
  const float* Wf  = (const float*)d_in[11];
  const float* bfc = (const float*)d_in[12];
  const float* W1  = (const float*)d_in[13];
  const float* b1  = (const float*)d_in[14];
  const float* W2  = (const float*)d_in[15];
  const float* b2  = (const float*)d_in[16];
  const float* g1  = (const float*)d_in[17];
  const float* be1 = (const float*)d_in[18];
  const float* g2  = (const float*)d_in[19];
  const float* be2 = (const float*)d_in[20];

  char* ws = (char*)d_ws;
  size_t off = 0;
  auto alloc = [&](size_t bytes) -> void* {
    void* p = ws + off;
    off += (bytes + 1023) & ~(size_t)1023;
    return p;
  };
  bf16*  xb    = (bf16*)alloc((size_t)NTOK * 512 * 2);
  bf16*  qkv   = (bf16*)alloc((size_t)NTOK * QKVW * 2);   // [q|k|v|qv]
  bf16*  vT    = (bf16*)alloc((size_t)BAT * 512 * SEQ * 2);
  bf16*  wtPk  = (bf16*)alloc((size_t)QKVW * 512 * 2);    // packed WqT|WkT|WvT|WqvT
  bf16*  WfT   = (bf16*)alloc(512 * 512 * 2);
  bf16*  W1T   = (bf16*)alloc((size_t)2048 * 512 * 2);
  bf16*  W2T   = (bf16*)alloc((size_t)512 * 2048 * 2);
  float* bcat  = (float*)alloc(QKVW * 4);
  bf16*  attn  = (bf16*)alloc((size_t)NTOK * 512 * 2);
  float* wfo   = (float*)alloc((size_t)NTOK * 512 * 4);   // aliased by ffn2 out
  float* ln1f  = (float*)alloc((size_t)NTOK * 512 * 4);
  bf16*  ln1b  = (bf16*)alloc((size_t)NTOK * 512 * 2);

  const size_t outbA = (size_t)BAT * NH * SEQ * 512 * 2;   // 64 MB
  const size_t pbufA = (size_t)BAT * NH * SEQ * SEQ * 2;   // 256 MB
  const size_t outbB = (size_t)NH * SEQ * 512 * 2;         // 16 MB
  const size_t pbufB = (size_t)NH * SEQ * SEQ * 2;         // 64 MB
  const bool bigP = ws_size >= off + outbA + pbufA + 4096;
  bf16* outb = (bf16*)alloc(bigP ? outbA : outbB);
  bf16* pbuf = (bf16*)alloc(bigP ? pbufA : pbufB);
  bf16* ffn1 = pbuf;          // 32 MB needed, fits both paths
  float* ffn2 = wfo;

  const dim3 tb(32, 8);
  // packed projection weights (scales baked in)
  transpose_w_kernel<<<dim3(16, 16), tb, 0, stream>>>(Wq,  wtPk,              512, 512, 0.125f);
  transpose_w_kernel<<<dim3(16, 16), tb, 0, stream>>>(Wk,  wtPk + 512  * 512, 512, 512, 1.f);
  transpose_w_kernel<<<dim3(16, 16), tb, 0, stream>>>(Wv,  wtPk + 1024 * 512, 512, 512, 1.f);
  transpose_w_kernel<<<dim3(8, 16),  tb, 0, stream>>>(Wqv, wtPk + 1536 * 512, 512, 256, 0.17677669529663687f);
  transpose_w_kernel<<<dim3(16, 16), tb, 0, stream>>>(Wf,  WfT, 512, 512, 1.f);
  transpose_w_kernel<<<dim3(64, 16), tb, 0, stream>>>(W1,  W1T, 512, 2048, 1.f);
  transpose_w_kernel<<<dim3(16, 64), tb, 0, stream>>>(W2,  W2T, 2048, 512, 1.f);
  build_bias_kernel<<<7, 256, 0, stream>>>(bq, bk, bv, bqv, bcat);
  convert_x_kernel<<<2048, 256, 0, stream>>>(x, xb);

  // fused q|k|v|qv projection: [8192,512] @ [1792,512]^T -> [8192,1792]
  gemm_bt<<<dim3(14, 64, 1), 256, 0, stream>>>(xb, wtPk, qkv, bcat,
      512, 512, 512, QKVW, 0, 0, 0, 1.f, 1);

  transpose_v_kernel<<<dim3(64, 16, 4), tb, 0, stream>>>(qkv, vT);

  const long sPb = (long)NH * SEQ * SEQ;       // P elems per batch
  const long sOb = (long)NH * SEQ * 512;       // outb elems per batch
  if (bigP) {
    for (int b = 0; b < BAT; b++) {
      const bf16* qB = qkv + (size_t)b * SEQ * QKVW;
      gemm_bt<<<dim3(16, 16, 8), 256, 0, stream>>>(qB, qB + 512, pbuf + (size_t)b * sPb,
          nullptr, 64, QKVW, QKVW, 2048, 64, 64, (long)SEQ * SEQ, 1.f, 1);
    }
    softmax_kernel<<<BAT * NH * SEQ, 256, 0, stream>>>(pbuf);
    // PV all batches: [16384,2048]@[2048,512] per z=batch
    gemm_bt<<<dim3(4, 128, 4), 256, 0, stream>>>(pbuf, vT, outb, nullptr,
        2048, 2048, 2048, 512, sPb, (long)512 * SEQ, sOb, 1.f, 1);
    stage2_kernel<<<BAT * NH * SEQ / 4, 256, 0, stream>>>(outb, sOb, qkv + 1536, QKVW,
        Wkv, bkv, attn, 0);
  } else {
    for (int b = 0; b < BAT; b++) {
      const bf16* qB = qkv + (size_t)b * SEQ * QKVW;
      gemm_bt<<<dim3(16, 16, 8), 256, 0, stream>>>(qB, qB + 512, pbuf, nullptr,
          64, QKVW, QKVW, 2048, 64, 64, (long)SEQ * SEQ, 1.f, 1);
      softmax_kernel<<<NH * SEQ, 256, 0, stream>>>(pbuf);
      gemm_bt<<<dim3(4, 128, 1), 256, 0, stream>>>(pbuf, vT + (size_t)b * 512 * SEQ,
          outb, nullptr, 2048, 2048, 2048, 512, 0, 0, 0, 1.f, 1);
      stage2_kernel<<<NH * SEQ / 4, 256, 0, stream>>>(outb, 0, qkv + 1536, QKVW,
          Wkv, bkv, attn, b * SEQ);
    }
  }

  gemm_bt<<<dim3(4, 64, 1), 256, 0, stream>>>(attn, WfT, wfo, bfc,
      512, 512, 512, 512, 0, 0, 0, 1.f, 0);
  ln_kernel<<<NTOK, 256, 0, stream>>>(wfo, x, 1, g1, be1, ln1f, ln1b, 0);
  gemm_bt<<<dim3(16, 64, 1), 256, 0, stream>>>(ln1b, W1T, ffn1, b1,
      512, 512, 512, 2048, 0, 0, 0, 1.f, 1 | 2);
  gemm_bt<<<dim3(4, 64, 1), 256, 0, stream>>>(ffn1, W2T, ffn2, b2,
      2048, 2048, 2048, 512, 0, 0, 0, 1.f, 0);
  ln_kernel<<<NTOK, 256, 0, stream>>>(ffn2, ln1f, 0, g2, be2, (float*)d_out, nullptr, 1);
}